// Round 1
// baseline (330.761 us; speedup 1.0000x reference)
//
#include <hip/hip_runtime.h>

// ---------- types ----------
typedef __attribute__((ext_vector_type(8))) short bf16x8;   // 8 bf16 = 4 VGPRs
typedef __attribute__((ext_vector_type(4))) float f32x4;    // MFMA acc

__device__ __forceinline__ unsigned short f2bf(float f) {
    unsigned int u = __float_as_uint(f);
    u += 0x7fffu + ((u >> 16) & 1u);          // round-to-nearest-even
    return (unsigned short)(u >> 16);
}
__device__ __forceinline__ float bf2f(unsigned short h) {
    return __uint_as_float(((unsigned int)h) << 16);
}

// ---------- cast kernels ----------
// x,y: [8192,256] f32 -> bf16. grid 2048 x 256, 4 elems/thread.
__global__ void cast_xy_kernel(const float* __restrict__ x, const float* __restrict__ y,
                               unsigned short* __restrict__ XB, unsigned short* __restrict__ YB)
{
    int idx = blockIdx.x * 256 + threadIdx.x;           // < 524288
    const float4 xv = ((const float4*)x)[idx];
    const float4 yv = ((const float4*)y)[idx];
    ushort4 a, b;
    a.x = f2bf(xv.x); a.y = f2bf(xv.y); a.z = f2bf(xv.z); a.w = f2bf(xv.w);
    b.x = f2bf(yv.x); b.y = f2bf(yv.y); b.z = f2bf(yv.z); b.w = f2bf(yv.w);
    ((ushort4*)XB)[idx] = a;
    ((ushort4*)YB)[idx] = b;
}

// w: [256(k),256(n)] f32 -> WT bf16 [256(n),256(k)]  (so xw GEMM is NT form)
__global__ void cast_wt_kernel(const float* __restrict__ w, unsigned short* __restrict__ WT)
{
    int idx = blockIdx.x * 256 + threadIdx.x;           // < 65536
    int k = idx >> 8, n = idx & 255;
    WT[n * 256 + k] = f2bf(w[idx]);
}

// ---------- NT GEMM, K=256 fixed, 128x128 tile, bf16 MFMA 16x16x32 ----------
// A: [M,256] bf16 row-major (rows = m), B: [N,256] bf16 row-major (rows = n)
// C[m,n] = sum_k A[m,k]*B[n,k]
// LSE==0: store C as bf16 to outp (row-major, leading dim Nld)
// LSE==1: per-column partial (max, sumexp) over the block's 128 rows,
//         written to float2 P[col*128 + rowtile], rowtile = m/64.
template<int LSE>
__global__ __launch_bounds__(256, 2)
void gemm_nt(const unsigned short* __restrict__ A,
             const unsigned short* __restrict__ B,
             void* __restrict__ outp, int Nld)
{
    __shared__ __align__(16) unsigned short As[128 * 64];  // 16 KB
    __shared__ __align__(16) unsigned short Bs[128 * 64];  // 16 KB

    const int tid  = threadIdx.x;
    const int lane = tid & 63;
    const int w    = tid >> 6;         // wave 0..3
    const int wm   = w >> 1, wn = w & 1;
    const int frow = lane & 15, quad = lane >> 4;
    const int rowBase = blockIdx.y * 128;
    const int colBase = blockIdx.x * 128;

    // Precompute LDS frag element offsets (loop-invariant; XOR-swizzled chunks).
    // LDS layout: row r (128 rows) x 8 chunks of 8 bf16; chunk kc stored at slot kc^(r&7).
    int aOff[4][2], bOff[4][2];
#pragma unroll
    for (int mi = 0; mi < 4; ++mi) {
#pragma unroll
        for (int kk = 0; kk < 2; ++kk) {
            int ka = kk * 4 + quad;                    // k chunk index (k = ka*8)
            int ra = wm * 64 + mi * 16 + frow;
            aOff[mi][kk] = ra * 64 + ((ka ^ (ra & 7)) << 3);
            int rb = wn * 64 + mi * 16 + frow;
            bOff[mi][kk] = rb * 64 + ((ka ^ (rb & 7)) << 3);
        }
    }

    f32x4 acc[4][4];
#pragma unroll
    for (int i = 0; i < 4; ++i)
#pragma unroll
        for (int j = 0; j < 4; ++j)
            acc[i][j] = f32x4{0.f, 0.f, 0.f, 0.f};

#pragma unroll
    for (int kt = 0; kt < 4; ++kt) {                   // K = 256, BK = 64
        const int k0 = kt * 64;
        // stage A and B tiles: 1024 16B-chunks each wave-lane-ordered (swizzled fetch)
#pragma unroll
        for (int it = 0; it < 4; ++it) {
            int p  = it * 256 + tid;                   // LDS chunk position
            int r  = p >> 3;
            int s  = p & 7;
            int kc = s ^ (r & 7);                      // which global chunk lands here
            const unsigned short* ga = A + (size_t)(rowBase + r) * 256 + k0 + (kc << 3);
            const unsigned short* gb = B + (size_t)(colBase + r) * 256 + k0 + (kc << 3);
            __builtin_amdgcn_global_load_lds(
                (const __attribute__((address_space(1))) void*)ga,
                (__attribute__((address_space(3))) void*)&As[p << 3], 16, 0, 0);
            __builtin_amdgcn_global_load_lds(
                (const __attribute__((address_space(1))) void*)gb,
                (__attribute__((address_space(3))) void*)&Bs[p << 3], 16, 0, 0);
        }
        __syncthreads();
#pragma unroll
        for (int kk = 0; kk < 2; ++kk) {               // 2 x K=32 per BK
            bf16x8 a[4], b[4];
#pragma unroll
            for (int mi = 0; mi < 4; ++mi) a[mi] = *(const bf16x8*)&As[aOff[mi][kk]];
#pragma unroll
            for (int ni = 0; ni < 4; ++ni) b[ni] = *(const bf16x8*)&Bs[bOff[ni][kk]];
#pragma unroll
            for (int mi = 0; mi < 4; ++mi)
#pragma unroll
                for (int ni = 0; ni < 4; ++ni)
                    acc[mi][ni] = __builtin_amdgcn_mfma_f32_16x16x32_bf16(
                        a[mi], b[ni], acc[mi][ni], 0, 0, 0);
        }
        __syncthreads();
    }

    if (LSE) {
        // C/D layout: col = lane&15, row = quad*4 + reg  [verified m89/m91]
        float2* P = (float2*)outp;
        const int rowtile = blockIdx.y * 2 + wm;       // 64-row granule index
#pragma unroll
        for (int ni = 0; ni < 4; ++ni) {
            float m = -1e30f;
#pragma unroll
            for (int mi = 0; mi < 4; ++mi)
#pragma unroll
                for (int r2 = 0; r2 < 4; ++r2) m = fmaxf(m, acc[mi][ni][r2]);
            m = fmaxf(m, __shfl_xor(m, 16));
            m = fmaxf(m, __shfl_xor(m, 32));
            float ssum = 0.f;
#pragma unroll
            for (int mi = 0; mi < 4; ++mi)
#pragma unroll
                for (int r2 = 0; r2 < 4; ++r2) ssum += __expf(acc[mi][ni][r2] - m);
            ssum += __shfl_xor(ssum, 16);
            ssum += __shfl_xor(ssum, 32);
            if (quad == 0) {
                int col = colBase + wn * 64 + ni * 16 + frow;
                P[(size_t)col * 128 + rowtile] = make_float2(m, ssum);
            }
        }
    } else {
        unsigned short* C = (unsigned short*)outp;
#pragma unroll
        for (int mi = 0; mi < 4; ++mi)
#pragma unroll
            for (int ni = 0; ni < 4; ++ni)
#pragma unroll
                for (int r2 = 0; r2 < 4; ++r2) {
                    int row = rowBase + wm * 64 + mi * 16 + quad * 4 + r2;
                    int col = colBase + wn * 64 + ni * 16 + frow;
                    C[(size_t)row * Nld + col] = f2bf(acc[mi][ni][r2]);
                }
    }
}

// ---------- diagonal: t0_sum = sum_i dot(XW[i,:], Y[i,:]) ----------
__global__ void diag_kernel(const unsigned short* __restrict__ XW,
                            const unsigned short* __restrict__ Y,
                            float* __restrict__ scal)
{
    int wid = threadIdx.x >> 6, lane = threadIdx.x & 63;
    int row = blockIdx.x * 4 + wid;
    const ushort4 xv = *(const ushort4*)&XW[(size_t)row * 256 + lane * 4];
    const ushort4 yv = *(const ushort4*)&Y[(size_t)row * 256 + lane * 4];
    float v = bf2f(xv.x) * bf2f(yv.x) + bf2f(xv.y) * bf2f(yv.y)
            + bf2f(xv.z) * bf2f(yv.z) + bf2f(xv.w) * bf2f(yv.w);
#pragma unroll
    for (int o = 1; o < 64; o <<= 1) v += __shfl_xor(v, o);
    if (lane == 0) atomicAdd(&scal[0], v);
}

// ---------- combine partials: lse_sum = sum_b logsumexp_i S[i,b] ----------
__global__ void combine_kernel(const float2* __restrict__ P, float* __restrict__ scal)
{
    int wid = threadIdx.x >> 6, lane = threadIdx.x & 63;
    int col = blockIdx.x * 4 + wid;
    float2 a = P[(size_t)col * 128 + lane];
    float2 b = P[(size_t)col * 128 + 64 + lane];
    float m = fmaxf(a.x, b.x);
#pragma unroll
    for (int o = 1; o < 64; o <<= 1) m = fmaxf(m, __shfl_xor(m, o));
    float s = a.y * __expf(a.x - m) + b.y * __expf(b.x - m);
#pragma unroll
    for (int o = 1; o < 64; o <<= 1) s += __shfl_xor(s, o);
    if (lane == 0) atomicAdd(&scal[1], logf(s) + m);
}

// ---------- finalize scalar ----------
__global__ void finalize_kernel(const float* __restrict__ scal, float* __restrict__ out)
{
    const float invN = 1.f / 8192.f;
    out[0] = scal[0] * invN - (scal[1] * invN - logf(8192.f));
}

// ---------- launch ----------
extern "C" void kernel_launch(void* const* d_in, const int* in_sizes, int n_in,
                              void* d_out, int out_size, void* d_ws, size_t ws_size,
                              hipStream_t stream)
{
    const float* x = (const float*)d_in[0];   // [8192,256]
    const float* y = (const float*)d_in[1];   // [8192,256]
    const float* w = (const float*)d_in[2];   // [256,256]
    float* out = (float*)d_out;

    char* ws = (char*)d_ws;
    unsigned short* XB  = (unsigned short*)(ws);              // 4 MB
    unsigned short* YB  = (unsigned short*)(ws + 0x400000);   // 4 MB
    unsigned short* XWB = (unsigned short*)(ws + 0x800000);   // 4 MB
    unsigned short* WT  = (unsigned short*)(ws + 0xC00000);   // 128 KB
    float2*         P   = (float2*)       (ws + 0xC20000);    // 8 MB
    float*          scal= (float*)        (ws + 0x1420000);   // 8 B

    hipMemsetAsync(scal, 0, 2 * sizeof(float), stream);
    cast_xy_kernel<<<2048, 256, 0, stream>>>(x, y, XB, YB);
    cast_wt_kernel<<<256, 256, 0, stream>>>(w, WT);
    // xw = x @ W  : A=XB [8192,256], B=WT [256,256] -> XWB bf16 [8192,256]
    gemm_nt<0><<<dim3(2, 64), 256, 0, stream>>>(XB, WT, (void*)XWB, 256);
    // S = xw @ y^T with fused per-column (max, sumexp) partials
    gemm_nt<1><<<dim3(64, 64), 256, 0, stream>>>(XWB, YB, (void*)P, 8192);
    diag_kernel<<<2048, 256, 0, stream>>>(XWB, YB, scal);
    combine_kernel<<<2048, 256, 0, stream>>>(P, scal);
    finalize_kernel<<<1, 1, 0, stream>>>(scal, out);
}

// Round 2
// 127.250 us; speedup vs baseline: 2.5993x; 2.5993x over previous
//
#include <hip/hip_runtime.h>

// ---------- types ----------
typedef __attribute__((ext_vector_type(8))) short bf16x8;   // 8 bf16 = 4 VGPRs
typedef __attribute__((ext_vector_type(4))) float f32x4;    // MFMA acc

__device__ __forceinline__ unsigned short f2bf(float f) {
    unsigned int u = __float_as_uint(f);
    u += 0x7fffu + ((u >> 16) & 1u);          // round-to-nearest-even
    return (unsigned short)(u >> 16);
}
__device__ __forceinline__ float bf2f(unsigned short h) {
    return __uint_as_float(((unsigned int)h) << 16);
}

// ---------- cast kernels ----------
__global__ void cast_xy_kernel(const float* __restrict__ x, const float* __restrict__ y,
                               unsigned short* __restrict__ XB, unsigned short* __restrict__ YB)
{
    int idx = blockIdx.x * 256 + threadIdx.x;           // < 524288
    const float4 xv = ((const float4*)x)[idx];
    const float4 yv = ((const float4*)y)[idx];
    ushort4 a, b;
    a.x = f2bf(xv.x); a.y = f2bf(xv.y); a.z = f2bf(xv.z); a.w = f2bf(xv.w);
    b.x = f2bf(yv.x); b.y = f2bf(yv.y); b.z = f2bf(yv.z); b.w = f2bf(yv.w);
    ((ushort4*)XB)[idx] = a;
    ((ushort4*)YB)[idx] = b;
}

// w: [256(k),256(n)] f32 -> WT bf16 [256(n),256(k)]  (so xw GEMM is NT form)
__global__ void cast_wt_kernel(const float* __restrict__ w, unsigned short* __restrict__ WT)
{
    int idx = blockIdx.x * 256 + threadIdx.x;           // < 65536
    int k = idx >> 8, n = idx & 255;
    WT[n * 256 + k] = f2bf(w[idx]);
}

// ---------- NT GEMM, K=256 fixed, 128x128 tile, bf16 MFMA 16x16x32 ----------
// A: [M,256] bf16 row-major, B: [N,256] bf16 row-major; C[m,n] = sum_k A[m,k]*B[n,k]
// LSE==0: store C as bf16 to outp (row-major, leading dim Nld)
// LSE==1: per-column partial (max, sumexp) over the block's rows ->
//         float2 P[rowtile*8192 + col], rowtile = global_row/64.
//         Diagonal blocks also accumulate sum_i S[i,i] into scal[0].
template<int LSE>
__global__ __launch_bounds__(256, 2)
void gemm_nt(const unsigned short* __restrict__ A,
             const unsigned short* __restrict__ B,
             void* __restrict__ outp, int Nld, float* __restrict__ scal)
{
    __shared__ __align__(16) unsigned short As[128 * 64];  // 16 KB
    __shared__ __align__(16) unsigned short Bs[128 * 64];  // 16 KB

    const int tid  = threadIdx.x;
    const int lane = tid & 63;
    const int w    = tid >> 6;         // wave 0..3
    const int wm   = w >> 1, wn = w & 1;
    const int frow = lane & 15, quad = lane >> 4;
    const int rowBase = blockIdx.y * 128;
    const int colBase = blockIdx.x * 128;

    // LDS layout: row r (128 rows) x 8 chunks of 8 bf16; chunk kc at slot kc^(r&7).
    int aOff[4][2], bOff[4][2];
#pragma unroll
    for (int mi = 0; mi < 4; ++mi) {
#pragma unroll
        for (int kk = 0; kk < 2; ++kk) {
            int ka = kk * 4 + quad;
            int ra = wm * 64 + mi * 16 + frow;
            aOff[mi][kk] = ra * 64 + ((ka ^ (ra & 7)) << 3);
            int rb = wn * 64 + mi * 16 + frow;
            bOff[mi][kk] = rb * 64 + ((ka ^ (rb & 7)) << 3);
        }
    }

    f32x4 acc[4][4];
#pragma unroll
    for (int i = 0; i < 4; ++i)
#pragma unroll
        for (int j = 0; j < 4; ++j)
            acc[i][j] = f32x4{0.f, 0.f, 0.f, 0.f};

#pragma unroll
    for (int kt = 0; kt < 4; ++kt) {                   // K = 256, BK = 64
        const int k0 = kt * 64;
#pragma unroll
        for (int it = 0; it < 4; ++it) {
            int p  = it * 256 + tid;
            int r  = p >> 3;
            int s  = p & 7;
            int kc = s ^ (r & 7);
            const unsigned short* ga = A + (size_t)(rowBase + r) * 256 + k0 + (kc << 3);
            const unsigned short* gb = B + (size_t)(colBase + r) * 256 + k0 + (kc << 3);
            __builtin_amdgcn_global_load_lds(
                (const __attribute__((address_space(1))) void*)ga,
                (__attribute__((address_space(3))) void*)&As[p << 3], 16, 0, 0);
            __builtin_amdgcn_global_load_lds(
                (const __attribute__((address_space(1))) void*)gb,
                (__attribute__((address_space(3))) void*)&Bs[p << 3], 16, 0, 0);
        }
        __syncthreads();
#pragma unroll
        for (int kk = 0; kk < 2; ++kk) {               // 2 x K=32 per BK
            bf16x8 a[4], b[4];
#pragma unroll
            for (int mi = 0; mi < 4; ++mi) a[mi] = *(const bf16x8*)&As[aOff[mi][kk]];
#pragma unroll
            for (int ni = 0; ni < 4; ++ni) b[ni] = *(const bf16x8*)&Bs[bOff[ni][kk]];
#pragma unroll
            for (int mi = 0; mi < 4; ++mi)
#pragma unroll
                for (int ni = 0; ni < 4; ++ni)
                    acc[mi][ni] = __builtin_amdgcn_mfma_f32_16x16x32_bf16(
                        a[mi], b[ni], acc[mi][ni], 0, 0, 0);
        }
        __syncthreads();
    }

    if (LSE) {
        // C/D layout: col = lane&15, row = quad*4 + reg  [verified m89/m91]
        float2* P = (float2*)outp;
        const int rowtile = blockIdx.y * 2 + wm;       // 64-row granule index
#pragma unroll
        for (int ni = 0; ni < 4; ++ni) {
            float m = -1e30f;
#pragma unroll
            for (int mi = 0; mi < 4; ++mi)
#pragma unroll
                for (int r2 = 0; r2 < 4; ++r2) m = fmaxf(m, acc[mi][ni][r2]);
            m = fmaxf(m, __shfl_xor(m, 16));
            m = fmaxf(m, __shfl_xor(m, 32));
            float ssum = 0.f;
#pragma unroll
            for (int mi = 0; mi < 4; ++mi)
#pragma unroll
                for (int r2 = 0; r2 < 4; ++r2) ssum += __expf(acc[mi][ni][r2] - m);
            ssum += __shfl_xor(ssum, 16);
            ssum += __shfl_xor(ssum, 32);
            if (quad == 0) {
                int col = colBase + wn * 64 + ni * 16 + frow;
                P[(size_t)rowtile * 8192 + col] = make_float2(m, ssum);
            }
        }
        // Fused diagonal: only diagonal blocks, only waves with wm==wn hold diag
        if (blockIdx.x == blockIdx.y && wm == wn) {
            float v = 0.f;
#pragma unroll
            for (int mi = 0; mi < 4; ++mi)
#pragma unroll
                for (int r2 = 0; r2 < 4; ++r2)
                    if (quad * 4 + r2 == frow) v += acc[mi][mi][r2];
#pragma unroll
            for (int o = 1; o < 64; o <<= 1) v += __shfl_xor(v, o);
            if (lane == 0) atomicAdd(&scal[0], v);     // 128 atomics total
        }
    } else {
        unsigned short* C = (unsigned short*)outp;
#pragma unroll
        for (int mi = 0; mi < 4; ++mi)
#pragma unroll
            for (int ni = 0; ni < 4; ++ni)
#pragma unroll
                for (int r2 = 0; r2 < 4; ++r2) {
                    int row = rowBase + wm * 64 + mi * 16 + quad * 4 + r2;
                    int col = colBase + wn * 64 + ni * 16 + frow;
                    C[(size_t)row * Nld + col] = f2bf(acc[mi][ni][r2]);
                }
    }
}

// ---------- combine partials: lse_sum = sum_b logsumexp_i S[i,b] ----------
// P layout: [128 rowtiles][8192 cols] float2(max, sumexp).
// One thread per column, coalesced across lanes; block reduce; 1 atomic/block.
__global__ void combine_kernel(const float2* __restrict__ P, float* __restrict__ scal)
{
    __shared__ float red[256];
    const int tid = threadIdx.x;
    const int col = blockIdx.x * 256 + tid;
    float m = -1e30f, s = 0.f;
#pragma unroll 8
    for (int j = 0; j < 128; ++j) {
        float2 v = P[(size_t)j * 8192 + col];
        float nm = fmaxf(m, v.x);
        s = s * __expf(m - nm) + v.y * __expf(v.x - nm);
        m = nm;
    }
    red[tid] = logf(s) + m;
    __syncthreads();
#pragma unroll
    for (int o = 128; o > 0; o >>= 1) {
        if (tid < o) red[tid] += red[tid + o];
        __syncthreads();
    }
    if (tid == 0) atomicAdd(&scal[1], red[0]);          // 32 atomics total
}

// ---------- finalize scalar ----------
__global__ void finalize_kernel(const float* __restrict__ scal, float* __restrict__ out)
{
    const float invN = 1.f / 8192.f;
    out[0] = scal[0] * invN - (scal[1] * invN - logf(8192.f));
}

// ---------- launch ----------
extern "C" void kernel_launch(void* const* d_in, const int* in_sizes, int n_in,
                              void* d_out, int out_size, void* d_ws, size_t ws_size,
                              hipStream_t stream)
{
    const float* x = (const float*)d_in[0];   // [8192,256]
    const float* y = (const float*)d_in[1];   // [8192,256]
    const float* w = (const float*)d_in[2];   // [256,256]
    float* out = (float*)d_out;

    char* ws = (char*)d_ws;
    unsigned short* XB  = (unsigned short*)(ws);              // 4 MB
    unsigned short* YB  = (unsigned short*)(ws + 0x400000);   // 4 MB
    unsigned short* XWB = (unsigned short*)(ws + 0x800000);   // 4 MB
    unsigned short* WT  = (unsigned short*)(ws + 0xC00000);   // 128 KB
    float2*         P   = (float2*)       (ws + 0xC20000);    // 8 MB
    float*          scal= (float*)        (ws + 0x1420000);   // 8 B

    hipMemsetAsync(scal, 0, 2 * sizeof(float), stream);
    cast_xy_kernel<<<2048, 256, 0, stream>>>(x, y, XB, YB);
    cast_wt_kernel<<<256, 256, 0, stream>>>(w, WT);
    // xw = x @ W  : A=XB [8192,256], B=WT [256,256] -> XWB bf16 [8192,256]
    gemm_nt<0><<<dim3(2, 64), 256, 0, stream>>>(XB, WT, (void*)XWB, 256, nullptr);
    // S = xw @ y^T with fused per-column (max, sumexp) partials + diag sum
    gemm_nt<1><<<dim3(64, 64), 256, 0, stream>>>(XWB, YB, (void*)P, 8192, scal);
    combine_kernel<<<32, 256, 0, stream>>>(P, scal);
    finalize_kernel<<<1, 1, 0, stream>>>(scal, out);
}

// Round 3
// 123.423 us; speedup vs baseline: 2.6799x; 1.0310x over previous
//
#include <hip/hip_runtime.h>

// ---------- types ----------
typedef __attribute__((ext_vector_type(8))) short bf16x8;   // 8 bf16 = 4 VGPRs
typedef __attribute__((ext_vector_type(4))) float f32x4;    // MFMA acc

__device__ __forceinline__ unsigned short f2bf(float f) {
    unsigned int u = __float_as_uint(f);
    u += 0x7fffu + ((u >> 16) & 1u);          // round-to-nearest-even
    return (unsigned short)(u >> 16);
}

// ---------- fused cast kernel: y -> bf16, W -> WT bf16, zero scalars ----------
// grid 2048 x 256
__global__ void cast_wy_kernel(const float* __restrict__ y, const float* __restrict__ w,
                               unsigned short* __restrict__ YB, unsigned short* __restrict__ WT,
                               float* __restrict__ scal)
{
    int idx = blockIdx.x * 256 + threadIdx.x;           // < 524288
    const float4 yv = ((const float4*)y)[idx];
    ushort4 b;
    b.x = f2bf(yv.x); b.y = f2bf(yv.y); b.z = f2bf(yv.z); b.w = f2bf(yv.w);
    ((ushort4*)YB)[idx] = b;
    // W: [256(k),256(n)] f32 -> WT [256(n),256(k)] bf16, blocks 0..63 only
    if (idx < 16384) {
        const float4 wv = ((const float4*)w)[idx];
        int k = idx >> 6;                // 4 floats/row-chunk, 64 chunks/row
        int n0 = (idx & 63) * 4;
        WT[(size_t)(n0 + 0) * 256 + k] = f2bf(wv.x);
        WT[(size_t)(n0 + 1) * 256 + k] = f2bf(wv.y);
        WT[(size_t)(n0 + 2) * 256 + k] = f2bf(wv.z);
        WT[(size_t)(n0 + 3) * 256 + k] = f2bf(wv.w);
    }
    if (idx == 0) {
        scal[0] = 0.f; scal[1] = 0.f;
        ((unsigned int*)scal)[2] = 0u;
    }
}

// ---------- gemm0: XW = X(f32) @ WT(bf16)^T -> XWB bf16 [8192,256] ----------
// A staged with on-the-fly f32->bf16 conversion; B via global_load_lds.
__global__ __launch_bounds__(256, 2)
void gemm0_kernel(const float* __restrict__ X, const unsigned short* __restrict__ WT,
                  unsigned short* __restrict__ XWB)
{
    __shared__ __align__(16) unsigned short As[128 * 64];  // 16 KB
    __shared__ __align__(16) unsigned short Bs[128 * 64];  // 16 KB

    const int tid  = threadIdx.x;
    const int lane = tid & 63;
    const int w    = tid >> 6;
    const int wm   = w >> 1, wn = w & 1;
    const int frow = lane & 15, quad = lane >> 4;
    const int rowBase = blockIdx.y * 128;
    const int colBase = blockIdx.x * 128;

    int aOff[4][2], bOff[4][2];
#pragma unroll
    for (int mi = 0; mi < 4; ++mi)
#pragma unroll
        for (int kk = 0; kk < 2; ++kk) {
            int ka = kk * 4 + quad;
            int ra = wm * 64 + mi * 16 + frow;
            aOff[mi][kk] = ra * 64 + ((ka ^ (ra & 7)) << 3);
            int rb = wn * 64 + mi * 16 + frow;
            bOff[mi][kk] = rb * 64 + ((ka ^ (rb & 7)) << 3);
        }

    f32x4 acc[4][4];
#pragma unroll
    for (int i = 0; i < 4; ++i)
#pragma unroll
        for (int j = 0; j < 4; ++j)
            acc[i][j] = f32x4{0.f, 0.f, 0.f, 0.f};

#pragma unroll
    for (int kt = 0; kt < 4; ++kt) {                   // K = 256, BK = 64
        const int k0 = kt * 64;
        // B tile: 1024 16B chunks via global_load_lds (swizzled)
#pragma unroll
        for (int it = 0; it < 4; ++it) {
            int p  = it * 256 + tid;
            int r  = p >> 3;
            int s  = p & 7;
            int kc = s ^ (r & 7);
            const unsigned short* gb = WT + (size_t)(colBase + r) * 256 + k0 + (kc << 3);
            __builtin_amdgcn_global_load_lds(
                (const __attribute__((address_space(1))) void*)gb,
                (__attribute__((address_space(3))) void*)&Bs[p << 3], 16, 0, 0);
        }
        // A tile: f32 load + convert + swizzled ds_write (8 float4 / thread)
#pragma unroll
        for (int it = 0; it < 8; ++it) {
            int fidx = it * 256 + tid;
            int r  = fidx >> 4;
            int c4 = fidx & 15;
            float4 v = *(const float4*)&X[(size_t)(rowBase + r) * 256 + k0 + c4 * 4];
            ushort4 u;
            u.x = f2bf(v.x); u.y = f2bf(v.y); u.z = f2bf(v.z); u.w = f2bf(v.w);
            int slot = (c4 >> 1) ^ (r & 7);
            *(ushort4*)&As[r * 64 + (slot << 3) + (c4 & 1) * 4] = u;
        }
        __syncthreads();
#pragma unroll
        for (int kk = 0; kk < 2; ++kk) {
            bf16x8 a[4], b[4];
#pragma unroll
            for (int mi = 0; mi < 4; ++mi) a[mi] = *(const bf16x8*)&As[aOff[mi][kk]];
#pragma unroll
            for (int ni = 0; ni < 4; ++ni) b[ni] = *(const bf16x8*)&Bs[bOff[ni][kk]];
#pragma unroll
            for (int mi = 0; mi < 4; ++mi)
#pragma unroll
                for (int ni = 0; ni < 4; ++ni)
                    acc[mi][ni] = __builtin_amdgcn_mfma_f32_16x16x32_bf16(
                        a[mi], b[ni], acc[mi][ni], 0, 0, 0);
        }
        __syncthreads();
    }

    // store bf16, C/D layout: col = lane&15, row = quad*4 + reg
#pragma unroll
    for (int mi = 0; mi < 4; ++mi)
#pragma unroll
        for (int ni = 0; ni < 4; ++ni)
#pragma unroll
            for (int r2 = 0; r2 < 4; ++r2) {
                int row = rowBase + wm * 64 + mi * 16 + quad * 4 + r2;
                int col = colBase + wn * 64 + ni * 16 + frow;
                XWB[(size_t)row * 256 + col] = f2bf(acc[mi][ni][r2]);
            }
}

// ---------- gemm1: S = XW @ Y^T fused with per-column LSE partials ----------
// Writes one f32 LSE per (128-row block, col): P[by*8192 + col].
// Diagonal blocks accumulate sum_i S[i,i] into scal[0].
__global__ __launch_bounds__(256, 3)
void gemm1_kernel(const unsigned short* __restrict__ A,
                  const unsigned short* __restrict__ B,
                  float* __restrict__ P, float* __restrict__ scal)
{
    __shared__ __align__(16) unsigned short As[128 * 64];  // 16 KB
    __shared__ __align__(16) unsigned short Bs[128 * 64];  // 16 KB
    __shared__ float lsebuf[256];                           // 1 KB

    const int tid  = threadIdx.x;
    const int lane = tid & 63;
    const int w    = tid >> 6;
    const int wm   = w >> 1, wn = w & 1;
    const int frow = lane & 15, quad = lane >> 4;
    const int rowBase = blockIdx.y * 128;
    const int colBase = blockIdx.x * 128;

    int aOff[4][2], bOff[4][2];
#pragma unroll
    for (int mi = 0; mi < 4; ++mi)
#pragma unroll
        for (int kk = 0; kk < 2; ++kk) {
            int ka = kk * 4 + quad;
            int ra = wm * 64 + mi * 16 + frow;
            aOff[mi][kk] = ra * 64 + ((ka ^ (ra & 7)) << 3);
            int rb = wn * 64 + mi * 16 + frow;
            bOff[mi][kk] = rb * 64 + ((ka ^ (rb & 7)) << 3);
        }

    f32x4 acc[4][4];
#pragma unroll
    for (int i = 0; i < 4; ++i)
#pragma unroll
        for (int j = 0; j < 4; ++j)
            acc[i][j] = f32x4{0.f, 0.f, 0.f, 0.f};

#pragma unroll
    for (int kt = 0; kt < 4; ++kt) {
        const int k0 = kt * 64;
#pragma unroll
        for (int it = 0; it < 4; ++it) {
            int p  = it * 256 + tid;
            int r  = p >> 3;
            int s  = p & 7;
            int kc = s ^ (r & 7);
            const unsigned short* ga = A + (size_t)(rowBase + r) * 256 + k0 + (kc << 3);
            const unsigned short* gb = B + (size_t)(colBase + r) * 256 + k0 + (kc << 3);
            __builtin_amdgcn_global_load_lds(
                (const __attribute__((address_space(1))) void*)ga,
                (__attribute__((address_space(3))) void*)&As[p << 3], 16, 0, 0);
            __builtin_amdgcn_global_load_lds(
                (const __attribute__((address_space(1))) void*)gb,
                (__attribute__((address_space(3))) void*)&Bs[p << 3], 16, 0, 0);
        }
        __syncthreads();
#pragma unroll
        for (int kk = 0; kk < 2; ++kk) {
            bf16x8 a[4], b[4];
#pragma unroll
            for (int mi = 0; mi < 4; ++mi) a[mi] = *(const bf16x8*)&As[aOff[mi][kk]];
#pragma unroll
            for (int ni = 0; ni < 4; ++ni) b[ni] = *(const bf16x8*)&Bs[bOff[ni][kk]];
#pragma unroll
            for (int mi = 0; mi < 4; ++mi)
#pragma unroll
                for (int ni = 0; ni < 4; ++ni)
                    acc[mi][ni] = __builtin_amdgcn_mfma_f32_16x16x32_bf16(
                        a[mi], b[ni], acc[mi][ni], 0, 0, 0);
        }
        __syncthreads();
    }

    // per-column LSE over this wave's 64 rows  (C/D: col=lane&15, row=quad*4+reg)
#pragma unroll
    for (int ni = 0; ni < 4; ++ni) {
        float m = -1e30f;
#pragma unroll
        for (int mi = 0; mi < 4; ++mi)
#pragma unroll
            for (int r2 = 0; r2 < 4; ++r2) m = fmaxf(m, acc[mi][ni][r2]);
        m = fmaxf(m, __shfl_xor(m, 16));
        m = fmaxf(m, __shfl_xor(m, 32));
        float ssum = 0.f;
#pragma unroll
        for (int mi = 0; mi < 4; ++mi)
#pragma unroll
            for (int r2 = 0; r2 < 4; ++r2) ssum += __expf(acc[mi][ni][r2] - m);
        ssum += __shfl_xor(ssum, 16);
        ssum += __shfl_xor(ssum, 32);
        if (quad == 0)
            lsebuf[wm * 128 + wn * 64 + ni * 16 + frow] = m + __logf(ssum);
    }
    // fused diagonal (before the epilogue barrier; acc only)
    if (blockIdx.x == blockIdx.y && wm == wn) {
        float v = 0.f;
#pragma unroll
        for (int mi = 0; mi < 4; ++mi)
#pragma unroll
            for (int r2 = 0; r2 < 4; ++r2)
                if (quad * 4 + r2 == frow) v += acc[mi][mi][r2];
#pragma unroll
        for (int o = 1; o < 64; o <<= 1) v += __shfl_xor(v, o);
        if (lane == 0) atomicAdd(&scal[0], v);          // 128 atomics total
    }
    __syncthreads();
    if (tid < 128) {
        float a = lsebuf[tid], b = lsebuf[128 + tid];
        float mm = fmaxf(a, b);
        P[(size_t)blockIdx.y * 8192 + colBase + tid]
            = mm + __logf(__expf(a - mm) + __expf(b - mm));
    }
}

// ---------- combine + finalize (last block writes out) ----------
// P: [64 rowblocks][8192 cols] f32 LSE partials.
__global__ void combine_kernel(const float* __restrict__ P, float* __restrict__ scal,
                               float* __restrict__ out)
{
    __shared__ float red[256];
    const int tid = threadIdx.x;
    const int col = blockIdx.x * 256 + tid;
    float m = -1e30f, s = 0.f;
#pragma unroll 8
    for (int j = 0; j < 64; ++j) {
        float v = P[(size_t)j * 8192 + col];
        float nm = fmaxf(m, v);
        s = s * __expf(m - nm) + __expf(v - nm);
        m = nm;
    }
    red[tid] = m + logf(s);
    __syncthreads();
#pragma unroll
    for (int o = 128; o > 0; o >>= 1) {
        if (tid < o) red[tid] += red[tid + o];
        __syncthreads();
    }
    if (tid == 0) {
        atomicAdd(&scal[1], red[0]);                    // 32 atomics total
        __threadfence();
        unsigned int old = __hip_atomic_fetch_add((unsigned int*)&scal[2], 1u,
                                                  __ATOMIC_ACQ_REL, __HIP_MEMORY_SCOPE_AGENT);
        if (old == 31u) {                               // last block finalizes
            float t0 = __hip_atomic_load(&scal[0], __ATOMIC_RELAXED, __HIP_MEMORY_SCOPE_AGENT);
            float ls = __hip_atomic_load(&scal[1], __ATOMIC_RELAXED, __HIP_MEMORY_SCOPE_AGENT);
            const float invN = 1.f / 8192.f;
            out[0] = t0 * invN - (ls * invN - logf(8192.f));
        }
    }
}

// ---------- launch ----------
extern "C" void kernel_launch(void* const* d_in, const int* in_sizes, int n_in,
                              void* d_out, int out_size, void* d_ws, size_t ws_size,
                              hipStream_t stream)
{
    const float* x = (const float*)d_in[0];   // [8192,256]
    const float* y = (const float*)d_in[1];   // [8192,256]
    const float* w = (const float*)d_in[2];   // [256,256]
    float* out = (float*)d_out;

    char* ws = (char*)d_ws;
    unsigned short* YB  = (unsigned short*)(ws);              // 4 MB
    unsigned short* XWB = (unsigned short*)(ws + 0x400000);   // 4 MB
    unsigned short* WT  = (unsigned short*)(ws + 0x800000);   // 128 KB
    float*          P   = (float*)        (ws + 0x820000);    // 2 MB
    float*          scal= (float*)        (ws + 0xA20000);    // 16 B

    cast_wy_kernel<<<2048, 256, 0, stream>>>(y, w, YB, WT, scal);
    gemm0_kernel<<<dim3(2, 64), 256, 0, stream>>>(x, WT, XWB);
    gemm1_kernel<<<dim3(64, 64), 256, 0, stream>>>(XWB, YB, P, scal);
    combine_kernel<<<32, 256, 0, stream>>>(P, scal, out);
}

// Round 4
// 113.975 us; speedup vs baseline: 2.9021x; 1.0829x over previous
//
#include <hip/hip_runtime.h>

// ---------- types ----------
typedef __attribute__((ext_vector_type(8))) short bf16x8;   // 8 bf16 = 4 VGPRs
typedef __attribute__((ext_vector_type(4))) float f32x4;    // MFMA acc
typedef __attribute__((ext_vector_type(8))) int   i32x8;    // 32-byte fp8 operand
typedef __attribute__((ext_vector_type(4))) int   i32x4;    // 16-byte half

union OpU { i32x8 v; i32x4 h[2]; };

__device__ __forceinline__ unsigned short f2bf(float f) {
    unsigned int u = __float_as_uint(f);
    u += 0x7fffu + ((u >> 16) & 1u);          // round-to-nearest-even
    return (unsigned short)(u >> 16);
}

// ---------- fused cast kernel: y -> fp8, W -> WT bf16, zero scalars ----------
// grid 2048 x 256
__global__ void cast_wy_kernel(const float* __restrict__ y, const float* __restrict__ w,
                               unsigned char* __restrict__ YQ, unsigned short* __restrict__ WT,
                               float* __restrict__ scal)
{
    int idx = blockIdx.x * 256 + threadIdx.x;           // < 524288
    const float4 yv = ((const float4*)y)[idx];
    int pk = __builtin_amdgcn_cvt_pk_fp8_f32(yv.x, yv.y, 0, 0);
    pk     = __builtin_amdgcn_cvt_pk_fp8_f32(yv.z, yv.w, pk, 1);
    ((int*)YQ)[idx] = pk;
    // W: [256(k),256(n)] f32 -> WT [256(n),256(k)] bf16
    if (idx < 16384) {
        const float4 wv = ((const float4*)w)[idx];
        int k = idx >> 6;
        int n0 = (idx & 63) * 4;
        WT[(size_t)(n0 + 0) * 256 + k] = f2bf(wv.x);
        WT[(size_t)(n0 + 1) * 256 + k] = f2bf(wv.y);
        WT[(size_t)(n0 + 2) * 256 + k] = f2bf(wv.z);
        WT[(size_t)(n0 + 3) * 256 + k] = f2bf(wv.w);
    }
    if (idx == 0) {
        scal[0] = 0.f; scal[1] = 0.f;
        ((unsigned int*)scal)[2] = 0u;
    }
}

// ---------- gemm0: XW = X(f32) @ WT(bf16)^T -> XWQ fp8 [8192,256] ----------
__global__ __launch_bounds__(256, 2)
void gemm0_kernel(const float* __restrict__ X, const unsigned short* __restrict__ WT,
                  unsigned char* __restrict__ XWQ)
{
    __shared__ __align__(16) unsigned short As[128 * 64];  // 16 KB
    __shared__ __align__(16) unsigned short Bs[128 * 64];  // 16 KB

    const int tid  = threadIdx.x;
    const int lane = tid & 63;
    const int w    = tid >> 6;
    const int wm   = w >> 1, wn = w & 1;
    const int frow = lane & 15, quad = lane >> 4;
    const int rowBase = blockIdx.y * 128;
    const int colBase = blockIdx.x * 128;

    int aOff[4][2], bOff[4][2];
#pragma unroll
    for (int mi = 0; mi < 4; ++mi)
#pragma unroll
        for (int kk = 0; kk < 2; ++kk) {
            int ka = kk * 4 + quad;
            int ra = wm * 64 + mi * 16 + frow;
            aOff[mi][kk] = ra * 64 + ((ka ^ (ra & 7)) << 3);
            int rb = wn * 64 + mi * 16 + frow;
            bOff[mi][kk] = rb * 64 + ((ka ^ (rb & 7)) << 3);
        }

    f32x4 acc[4][4];
#pragma unroll
    for (int i = 0; i < 4; ++i)
#pragma unroll
        for (int j = 0; j < 4; ++j)
            acc[i][j] = f32x4{0.f, 0.f, 0.f, 0.f};

#pragma unroll
    for (int kt = 0; kt < 4; ++kt) {                   // K = 256, BK = 64
        const int k0 = kt * 64;
#pragma unroll
        for (int it = 0; it < 4; ++it) {
            int p  = it * 256 + tid;
            int r  = p >> 3;
            int s  = p & 7;
            int kc = s ^ (r & 7);
            const unsigned short* gb = WT + (size_t)(colBase + r) * 256 + k0 + (kc << 3);
            __builtin_amdgcn_global_load_lds(
                (const __attribute__((address_space(1))) void*)gb,
                (__attribute__((address_space(3))) void*)&Bs[p << 3], 16, 0, 0);
        }
#pragma unroll
        for (int it = 0; it < 8; ++it) {
            int fidx = it * 256 + tid;
            int r  = fidx >> 4;
            int c4 = fidx & 15;
            float4 v = *(const float4*)&X[(size_t)(rowBase + r) * 256 + k0 + c4 * 4];
            ushort4 u;
            u.x = f2bf(v.x); u.y = f2bf(v.y); u.z = f2bf(v.z); u.w = f2bf(v.w);
            int slot = (c4 >> 1) ^ (r & 7);
            *(ushort4*)&As[r * 64 + (slot << 3) + (c4 & 1) * 4] = u;
        }
        __syncthreads();
#pragma unroll
        for (int kk = 0; kk < 2; ++kk) {
            bf16x8 a[4], b[4];
#pragma unroll
            for (int mi = 0; mi < 4; ++mi) a[mi] = *(const bf16x8*)&As[aOff[mi][kk]];
#pragma unroll
            for (int ni = 0; ni < 4; ++ni) b[ni] = *(const bf16x8*)&Bs[bOff[ni][kk]];
#pragma unroll
            for (int mi = 0; mi < 4; ++mi)
#pragma unroll
                for (int ni = 0; ni < 4; ++ni)
                    acc[mi][ni] = __builtin_amdgcn_mfma_f32_16x16x32_bf16(
                        a[mi], b[ni], acc[mi][ni], 0, 0, 0);
        }
        __syncthreads();
    }

    // store fp8, C/D layout: col = lane&15, row = quad*4 + reg
#pragma unroll
    for (int mi = 0; mi < 4; ++mi)
#pragma unroll
        for (int ni = 0; ni < 4; ++ni)
#pragma unroll
            for (int r2 = 0; r2 < 4; ++r2) {
                int row = rowBase + wm * 64 + mi * 16 + quad * 4 + r2;
                int col = colBase + wn * 64 + ni * 16 + frow;
                float v = acc[mi][ni][r2];
                int q = __builtin_amdgcn_cvt_pk_fp8_f32(v, v, 0, 0);
                XWQ[(size_t)row * 256 + col] = (unsigned char)(q & 0xff);
            }
}

// ---------- gemm1: S = XW @ Y^T (fp8, MX-scaled MFMA) + fused LSE ----------
// A = XWQ [8192,256] fp8, B = YQ [8192,256] fp8.
// Whole-K staging (32 KB per matrix), one staging barrier, 2 MFMA K-steps of
// mfma_scale_f32_16x16x128_f8f6f4 with unit scales (e8m0 127 = 1.0).
// Writes one f32 LSE per (128-row block, col): P[by*8192 + col].
// Diagonal blocks accumulate sum_i S[i,i] into scal[0].
__global__ __launch_bounds__(256, 2)
void gemm1_kernel(const unsigned char* __restrict__ A,
                  const unsigned char* __restrict__ B,
                  float* __restrict__ P, float* __restrict__ scal)
{
    __shared__ __align__(16) unsigned char As[128 * 256]; // 32 KB
    __shared__ __align__(16) unsigned char Bs[128 * 256]; // 32 KB
    float* lsebuf = (float*)As;    // aliased after compute (barrier-protected)

    const int tid  = threadIdx.x;
    const int lane = tid & 63;
    const int w    = tid >> 6;
    const int wm   = w >> 1, wn = w & 1;
    const int frow = lane & 15, quad = lane >> 4;
    const int rowBase = blockIdx.y * 128;
    const int colBase = blockIdx.x * 128;

    // stage full-K tiles: 2048 16B chunks per matrix, 8 per thread.
    // LDS row r holds its 16 chunks with chunk c at slot c^(r&15) (XOR swizzle).
#pragma unroll
    for (int it = 0; it < 8; ++it) {
        int p  = it * 256 + tid;
        int r  = p >> 4;
        int s  = p & 15;
        int kc = s ^ (r & 15);
        const unsigned char* ga = A + (size_t)(rowBase + r) * 256 + (kc << 4);
        const unsigned char* gb = B + (size_t)(colBase + r) * 256 + (kc << 4);
        __builtin_amdgcn_global_load_lds(
            (const __attribute__((address_space(1))) void*)ga,
            (__attribute__((address_space(3))) void*)&As[p << 4], 16, 0, 0);
        __builtin_amdgcn_global_load_lds(
            (const __attribute__((address_space(1))) void*)gb,
            (__attribute__((address_space(3))) void*)&Bs[p << 4], 16, 0, 0);
    }
    __syncthreads();

    f32x4 acc[4][4];
#pragma unroll
    for (int i = 0; i < 4; ++i)
#pragma unroll
        for (int j = 0; j < 4; ++j)
            acc[i][j] = f32x4{0.f, 0.f, 0.f, 0.f};

#pragma unroll
    for (int kk = 0; kk < 2; ++kk) {                   // K = 256 = 2 x 128
        const int c0 = kk * 8 + quad * 2;              // first 16B chunk of frag
        i32x8 a[4], b[4];
#pragma unroll
        for (int mi = 0; mi < 4; ++mi) {
            int ra = wm * 64 + mi * 16 + frow;         // (ra & 15) == frow
            OpU u;
            u.h[0] = *(const i32x4*)&As[ra * 256 + ((c0 ^ frow) << 4)];
            u.h[1] = *(const i32x4*)&As[ra * 256 + (((c0 + 1) ^ frow) << 4)];
            a[mi] = u.v;
        }
#pragma unroll
        for (int ni = 0; ni < 4; ++ni) {
            int rb = wn * 64 + ni * 16 + frow;
            OpU u;
            u.h[0] = *(const i32x4*)&Bs[rb * 256 + ((c0 ^ frow) << 4)];
            u.h[1] = *(const i32x4*)&Bs[rb * 256 + (((c0 + 1) ^ frow) << 4)];
            b[ni] = u.v;
        }
#pragma unroll
        for (int mi = 0; mi < 4; ++mi)
#pragma unroll
            for (int ni = 0; ni < 4; ++ni)
                acc[mi][ni] = __builtin_amdgcn_mfma_scale_f32_16x16x128_f8f6f4(
                    a[mi], b[ni], acc[mi][ni],
                    0, 0,                      // cbsz=fp8(e4m3), blgp=fp8(e4m3)
                    0, 0x7f7f7f7f,             // scale A: byte0 = 127 -> 1.0
                    0, 0x7f7f7f7f);            // scale B: byte0 = 127 -> 1.0
    }

    __syncthreads();   // all LDS reads done; As may be reused as lsebuf

    // per-column LSE over this wave's 64 rows  (C/D: col=lane&15, row=quad*4+reg)
#pragma unroll
    for (int ni = 0; ni < 4; ++ni) {
        float m = -1e30f;
#pragma unroll
        for (int mi = 0; mi < 4; ++mi)
#pragma unroll
            for (int r2 = 0; r2 < 4; ++r2) m = fmaxf(m, acc[mi][ni][r2]);
        m = fmaxf(m, __shfl_xor(m, 16));
        m = fmaxf(m, __shfl_xor(m, 32));
        float ssum = 0.f;
#pragma unroll
        for (int mi = 0; mi < 4; ++mi)
#pragma unroll
            for (int r2 = 0; r2 < 4; ++r2) ssum += __expf(acc[mi][ni][r2] - m);
        ssum += __shfl_xor(ssum, 16);
        ssum += __shfl_xor(ssum, 32);
        if (quad == 0)
            lsebuf[wm * 128 + wn * 64 + ni * 16 + frow] = m + __logf(ssum);
    }
    // fused diagonal
    if (blockIdx.x == blockIdx.y && wm == wn) {
        float v = 0.f;
#pragma unroll
        for (int mi = 0; mi < 4; ++mi)
#pragma unroll
            for (int r2 = 0; r2 < 4; ++r2)
                if (quad * 4 + r2 == frow) v += acc[mi][mi][r2];
#pragma unroll
        for (int o = 1; o < 64; o <<= 1) v += __shfl_xor(v, o);
        if (lane == 0) atomicAdd(&scal[0], v);          // 128 atomics total
    }
    __syncthreads();
    if (tid < 128) {
        float a = lsebuf[tid], b = lsebuf[128 + tid];
        float mm = fmaxf(a, b);
        P[(size_t)blockIdx.y * 8192 + colBase + tid]
            = mm + __logf(__expf(a - mm) + __expf(b - mm));
    }
}

// ---------- combine + finalize (last block writes out) ----------
// P: [64 rowblocks][8192 cols] f32 LSE partials.
__global__ void combine_kernel(const float* __restrict__ P, float* __restrict__ scal,
                               float* __restrict__ out)
{
    __shared__ float red[256];
    const int tid = threadIdx.x;
    const int col = blockIdx.x * 256 + tid;
    float m = -1e30f, s = 0.f;
#pragma unroll 8
    for (int j = 0; j < 64; ++j) {
        float v = P[(size_t)j * 8192 + col];
        float nm = fmaxf(m, v);
        s = s * __expf(m - nm) + __expf(v - nm);
        m = nm;
    }
    red[tid] = m + logf(s);
    __syncthreads();
#pragma unroll
    for (int o = 128; o > 0; o >>= 1) {
        if (tid < o) red[tid] += red[tid + o];
        __syncthreads();
    }
    if (tid == 0) {
        atomicAdd(&scal[1], red[0]);                    // 32 atomics total
        __threadfence();
        unsigned int old = __hip_atomic_fetch_add((unsigned int*)&scal[2], 1u,
                                                  __ATOMIC_ACQ_REL, __HIP_MEMORY_SCOPE_AGENT);
        if (old == 31u) {                               // last block finalizes
            float t0 = __hip_atomic_load(&scal[0], __ATOMIC_RELAXED, __HIP_MEMORY_SCOPE_AGENT);
            float ls = __hip_atomic_load(&scal[1], __ATOMIC_RELAXED, __HIP_MEMORY_SCOPE_AGENT);
            const float invN = 1.f / 8192.f;
            out[0] = t0 * invN - (ls * invN - logf(8192.f));
        }
    }
}

// ---------- launch ----------
extern "C" void kernel_launch(void* const* d_in, const int* in_sizes, int n_in,
                              void* d_out, int out_size, void* d_ws, size_t ws_size,
                              hipStream_t stream)
{
    const float* x = (const float*)d_in[0];   // [8192,256]
    const float* y = (const float*)d_in[1];   // [8192,256]
    const float* w = (const float*)d_in[2];   // [256,256]
    float* out = (float*)d_out;

    char* ws = (char*)d_ws;
    unsigned char*  YQ  = (unsigned char*)(ws);               // 2 MB
    unsigned char*  XWQ = (unsigned char*)(ws + 0x200000);    // 2 MB
    unsigned short* WT  = (unsigned short*)(ws + 0x400000);   // 128 KB
    float*          P   = (float*)        (ws + 0x420000);    // 2 MB
    float*          scal= (float*)        (ws + 0x620000);    // 16 B

    cast_wy_kernel<<<2048, 256, 0, stream>>>(y, w, YQ, WT, scal);
    gemm0_kernel<<<dim3(2, 64), 256, 0, stream>>>(x, WT, XWQ);
    gemm1_kernel<<<dim3(64, 64), 256, 0, stream>>>(XWQ, YQ, P, scal);
    combine_kernel<<<32, 256, 0, stream>>>(P, scal, out);
}

// Round 5
// 111.728 us; speedup vs baseline: 2.9604x; 1.0201x over previous
//
#include <hip/hip_runtime.h>

// ---------- types ----------
typedef __attribute__((ext_vector_type(8))) short bf16x8;   // 8 bf16 = 4 VGPRs
typedef __attribute__((ext_vector_type(4))) float f32x4;    // MFMA acc
typedef __attribute__((ext_vector_type(8))) int   i32x8;    // 32-byte fp8 operand
typedef __attribute__((ext_vector_type(4))) int   i32x4;    // 16-byte half

union OpU { i32x8 v; i32x4 h[2]; };

__device__ __forceinline__ unsigned short f2bf(float f) {
    unsigned int u = __float_as_uint(f);
    u += 0x7fffu + ((u >> 16) & 1u);          // round-to-nearest-even
    return (unsigned short)(u >> 16);
}

// ---------- fused cast kernel: y -> fp8, W -> WT bf16, zero scalars ----------
// grid 2048 x 256
__global__ void cast_wy_kernel(const float* __restrict__ y, const float* __restrict__ w,
                               unsigned char* __restrict__ YQ, unsigned short* __restrict__ WT,
                               float* __restrict__ scal)
{
    int idx = blockIdx.x * 256 + threadIdx.x;           // < 524288
    const float4 yv = ((const float4*)y)[idx];
    int pk = __builtin_amdgcn_cvt_pk_fp8_f32(yv.x, yv.y, 0, 0);
    pk     = __builtin_amdgcn_cvt_pk_fp8_f32(yv.z, yv.w, pk, 1);
    ((int*)YQ)[idx] = pk;
    // W: [256(k),256(n)] f32 -> WT [256(n),256(k)] bf16
    if (idx < 16384) {
        const float4 wv = ((const float4*)w)[idx];
        int k = idx >> 6;
        int n0 = (idx & 63) * 4;
        WT[(size_t)(n0 + 0) * 256 + k] = f2bf(wv.x);
        WT[(size_t)(n0 + 1) * 256 + k] = f2bf(wv.y);
        WT[(size_t)(n0 + 2) * 256 + k] = f2bf(wv.z);
        WT[(size_t)(n0 + 3) * 256 + k] = f2bf(wv.w);
    }
    if (idx == 0) {
        scal[0] = 0.f; scal[1] = 0.f;
        ((unsigned int*)scal)[2] = 0u;
    }
}

// ---------- gemm0: XW = X(f32) @ WT(bf16)^T -> XWQ fp8 [8192,256] ----------
// 64x64 tile, grid (4,128) = 512 blocks (full-chip). 4 waves in 2x2.
__global__ __launch_bounds__(256, 4)
void gemm0_kernel(const float* __restrict__ X, const unsigned short* __restrict__ WT,
                  unsigned char* __restrict__ XWQ)
{
    __shared__ __align__(16) unsigned short As[64 * 64];   // 8 KB
    __shared__ __align__(16) unsigned short Bs[64 * 64];   // 8 KB

    const int tid  = threadIdx.x;
    const int lane = tid & 63;
    const int w    = tid >> 6;
    const int wm   = w >> 1, wn = w & 1;
    const int frow = lane & 15, quad = lane >> 4;
    const int rowBase = blockIdx.y * 64;
    const int colBase = blockIdx.x * 64;

    int aOff[2][2], bOff[2][2];
#pragma unroll
    for (int mi = 0; mi < 2; ++mi)
#pragma unroll
        for (int kk = 0; kk < 2; ++kk) {
            int ka = kk * 4 + quad;
            int ra = wm * 32 + mi * 16 + frow;
            aOff[mi][kk] = ra * 64 + ((ka ^ (ra & 7)) << 3);
            int rb = wn * 32 + mi * 16 + frow;
            bOff[mi][kk] = rb * 64 + ((ka ^ (rb & 7)) << 3);
        }

    f32x4 acc[2][2];
#pragma unroll
    for (int i = 0; i < 2; ++i)
#pragma unroll
        for (int j = 0; j < 2; ++j)
            acc[i][j] = f32x4{0.f, 0.f, 0.f, 0.f};

#pragma unroll
    for (int kt = 0; kt < 4; ++kt) {                   // K = 256, BK = 64
        const int k0 = kt * 64;
        // B tile: 64 rows x 8 chunks(16B) = 512 chunks -> 2/thread
#pragma unroll
        for (int it = 0; it < 2; ++it) {
            int p  = it * 256 + tid;
            int r  = p >> 3;
            int s  = p & 7;
            int kc = s ^ (r & 7);
            const unsigned short* gb = WT + (size_t)(colBase + r) * 256 + k0 + (kc << 3);
            __builtin_amdgcn_global_load_lds(
                (const __attribute__((address_space(1))) void*)gb,
                (__attribute__((address_space(3))) void*)&Bs[p << 3], 16, 0, 0);
        }
        // A tile: 64 rows x 64 k f32 -> bf16 (1024 float4 -> 4/thread)
#pragma unroll
        for (int it = 0; it < 4; ++it) {
            int fidx = it * 256 + tid;
            int r  = fidx >> 4;
            int c4 = fidx & 15;
            float4 v = *(const float4*)&X[(size_t)(rowBase + r) * 256 + k0 + c4 * 4];
            ushort4 u;
            u.x = f2bf(v.x); u.y = f2bf(v.y); u.z = f2bf(v.z); u.w = f2bf(v.w);
            int slot = (c4 >> 1) ^ (r & 7);
            *(ushort4*)&As[r * 64 + (slot << 3) + (c4 & 1) * 4] = u;
        }
        __syncthreads();
#pragma unroll
        for (int kk = 0; kk < 2; ++kk) {
            bf16x8 a[2], b[2];
#pragma unroll
            for (int mi = 0; mi < 2; ++mi) a[mi] = *(const bf16x8*)&As[aOff[mi][kk]];
#pragma unroll
            for (int ni = 0; ni < 2; ++ni) b[ni] = *(const bf16x8*)&Bs[bOff[ni][kk]];
#pragma unroll
            for (int mi = 0; mi < 2; ++mi)
#pragma unroll
                for (int ni = 0; ni < 2; ++ni)
                    acc[mi][ni] = __builtin_amdgcn_mfma_f32_16x16x32_bf16(
                        a[mi], b[ni], acc[mi][ni], 0, 0, 0);
        }
        __syncthreads();
    }

    // store fp8, C/D layout: col = lane&15, row = quad*4 + reg
#pragma unroll
    for (int mi = 0; mi < 2; ++mi)
#pragma unroll
        for (int ni = 0; ni < 2; ++ni)
#pragma unroll
            for (int r2 = 0; r2 < 4; ++r2) {
                int row = rowBase + wm * 32 + mi * 16 + quad * 4 + r2;
                int col = colBase + wn * 32 + ni * 16 + frow;
                float v = acc[mi][ni][r2];
                int q = __builtin_amdgcn_cvt_pk_fp8_f32(v, v, 0, 0);
                XWQ[(size_t)row * 256 + col] = (unsigned char)(q & 0xff);
            }
}

// ---------- gemm1: S = XW @ Y^T (fp8, MX-scaled MFMA) + fused LSE ----------
// 128x128 tile, BK=128 (2-step K loop), 16 KB + 16 KB LDS -> 3 blocks/CU.
// mfma_scale_f32_16x16x128_f8f6f4 with unit scales (e8m0 127 = 1.0).
// Writes one f32 LSE per (128-row block, col): P[by*8192 + col].
// Diagonal blocks accumulate sum_i S[i,i] into scal[0].
__global__ __launch_bounds__(256, 3)
void gemm1_kernel(const unsigned char* __restrict__ A,
                  const unsigned char* __restrict__ B,
                  float* __restrict__ P, float* __restrict__ scal)
{
    __shared__ __align__(16) unsigned char As[128 * 128]; // 16 KB
    __shared__ __align__(16) unsigned char Bs[128 * 128]; // 16 KB
    __shared__ float lsebuf[256];                          // 1 KB

    const int tid  = threadIdx.x;
    const int lane = tid & 63;
    const int w    = tid >> 6;
    const int wm   = w >> 1, wn = w & 1;
    const int frow = lane & 15, quad = lane >> 4;
    const int rowBase = blockIdx.y * 128;
    const int colBase = blockIdx.x * 128;

    f32x4 acc[4][4];
#pragma unroll
    for (int i = 0; i < 4; ++i)
#pragma unroll
        for (int j = 0; j < 4; ++j)
            acc[i][j] = f32x4{0.f, 0.f, 0.f, 0.f};

#pragma unroll
    for (int kt = 0; kt < 2; ++kt) {                   // K = 256 = 2 x 128
        const int k0 = kt * 128;
        // stage: per matrix 128 rows x 8 chunks(16B) = 1024 chunks -> 4/thread
        // LDS row r: chunk kc stored at slot kc^(r&7) (XOR swizzle).
#pragma unroll
        for (int it = 0; it < 4; ++it) {
            int p  = it * 256 + tid;
            int r  = p >> 3;
            int s  = p & 7;
            int kc = s ^ (r & 7);
            const unsigned char* ga = A + (size_t)(rowBase + r) * 256 + k0 + (kc << 4);
            const unsigned char* gb = B + (size_t)(colBase + r) * 256 + k0 + (kc << 4);
            __builtin_amdgcn_global_load_lds(
                (const __attribute__((address_space(1))) void*)ga,
                (__attribute__((address_space(3))) void*)&As[p << 4], 16, 0, 0);
            __builtin_amdgcn_global_load_lds(
                (const __attribute__((address_space(1))) void*)gb,
                (__attribute__((address_space(3))) void*)&Bs[p << 4], 16, 0, 0);
        }
        __syncthreads();

        // fragments: lane (frow,quad) reads k-bytes [quad*32, quad*32+32)
        const int c0 = quad * 2;
        i32x8 a[4], b[4];
#pragma unroll
        for (int mi = 0; mi < 4; ++mi) {
            int ra = wm * 64 + mi * 16 + frow;         // (ra&7) == (frow&7)
            OpU u;
            u.h[0] = *(const i32x4*)&As[ra * 128 + ((c0 ^ (ra & 7)) << 4)];
            u.h[1] = *(const i32x4*)&As[ra * 128 + (((c0 + 1) ^ (ra & 7)) << 4)];
            a[mi] = u.v;
        }
#pragma unroll
        for (int ni = 0; ni < 4; ++ni) {
            int rb = wn * 64 + ni * 16 + frow;
            OpU u;
            u.h[0] = *(const i32x4*)&Bs[rb * 128 + ((c0 ^ (rb & 7)) << 4)];
            u.h[1] = *(const i32x4*)&Bs[rb * 128 + (((c0 + 1) ^ (rb & 7)) << 4)];
            b[ni] = u.v;
        }
#pragma unroll
        for (int mi = 0; mi < 4; ++mi)
#pragma unroll
            for (int ni = 0; ni < 4; ++ni)
                acc[mi][ni] = __builtin_amdgcn_mfma_scale_f32_16x16x128_f8f6f4(
                    a[mi], b[ni], acc[mi][ni],
                    0, 0,                      // cbsz=fp8(e4m3), blgp=fp8(e4m3)
                    0, 0x7f7f7f7f,             // scale A: byte0 = 127 -> 1.0
                    0, 0x7f7f7f7f);            // scale B: byte0 = 127 -> 1.0
        __syncthreads();
    }

    // per-column LSE over this wave's 64 rows  (C/D: col=lane&15, row=quad*4+reg)
#pragma unroll
    for (int ni = 0; ni < 4; ++ni) {
        float m = -1e30f;
#pragma unroll
        for (int mi = 0; mi < 4; ++mi)
#pragma unroll
            for (int r2 = 0; r2 < 4; ++r2) m = fmaxf(m, acc[mi][ni][r2]);
        m = fmaxf(m, __shfl_xor(m, 16));
        m = fmaxf(m, __shfl_xor(m, 32));
        float ssum = 0.f;
#pragma unroll
        for (int mi = 0; mi < 4; ++mi)
#pragma unroll
            for (int r2 = 0; r2 < 4; ++r2) ssum += __expf(acc[mi][ni][r2] - m);
        ssum += __shfl_xor(ssum, 16);
        ssum += __shfl_xor(ssum, 32);
        if (quad == 0)
            lsebuf[wm * 128 + wn * 64 + ni * 16 + frow] = m + __logf(ssum);
    }
    // fused diagonal
    if (blockIdx.x == blockIdx.y && wm == wn) {
        float v = 0.f;
#pragma unroll
        for (int mi = 0; mi < 4; ++mi)
#pragma unroll
            for (int r2 = 0; r2 < 4; ++r2)
                if (quad * 4 + r2 == frow) v += acc[mi][mi][r2];
#pragma unroll
        for (int o = 1; o < 64; o <<= 1) v += __shfl_xor(v, o);
        if (lane == 0) atomicAdd(&scal[0], v);          // 128 atomics total
    }
    __syncthreads();
    if (tid < 128) {
        float a = lsebuf[tid], b = lsebuf[128 + tid];
        float mm = fmaxf(a, b);
        P[(size_t)blockIdx.y * 8192 + colBase + tid]
            = mm + __logf(__expf(a - mm) + __expf(b - mm));
    }
}

// ---------- combine + finalize (last block writes out) ----------
// P: [64 rowblocks][8192 cols] f32 LSE partials.
__global__ void combine_kernel(const float* __restrict__ P, float* __restrict__ scal,
                               float* __restrict__ out)
{
    __shared__ float red[256];
    const int tid = threadIdx.x;
    const int col = blockIdx.x * 256 + tid;
    float m = -1e30f, s = 0.f;
#pragma unroll 8
    for (int j = 0; j < 64; ++j) {
        float v = P[(size_t)j * 8192 + col];
        float nm = fmaxf(m, v);
        s = s * __expf(m - nm) + __expf(v - nm);
        m = nm;
    }
    red[tid] = m + logf(s);
    __syncthreads();
#pragma unroll
    for (int o = 128; o > 0; o >>= 1) {
        if (tid < o) red[tid] += red[tid + o];
        __syncthreads();
    }
    if (tid == 0) {
        atomicAdd(&scal[1], red[0]);                    // 32 atomics total
        __threadfence();
        unsigned int old = __hip_atomic_fetch_add((unsigned int*)&scal[2], 1u,
                                                  __ATOMIC_ACQ_REL, __HIP_MEMORY_SCOPE_AGENT);
        if (old == 31u) {                               // last block finalizes
            float t0 = __hip_atomic_load(&scal[0], __ATOMIC_RELAXED, __HIP_MEMORY_SCOPE_AGENT);
            float ls = __hip_atomic_load(&scal[1], __ATOMIC_RELAXED, __HIP_MEMORY_SCOPE_AGENT);
            const float invN = 1.f / 8192.f;
            out[0] = t0 * invN - (ls * invN - logf(8192.f));
        }
    }
}

// ---------- launch ----------
extern "C" void kernel_launch(void* const* d_in, const int* in_sizes, int n_in,
                              void* d_out, int out_size, void* d_ws, size_t ws_size,
                              hipStream_t stream)
{
    const float* x = (const float*)d_in[0];   // [8192,256]
    const float* y = (const float*)d_in[1];   // [8192,256]
    const float* w = (const float*)d_in[2];   // [256,256]
    float* out = (float*)d_out;

    char* ws = (char*)d_ws;
    unsigned char*  YQ  = (unsigned char*)(ws);               // 2 MB
    unsigned char*  XWQ = (unsigned char*)(ws + 0x200000);    // 2 MB
    unsigned short* WT  = (unsigned short*)(ws + 0x400000);   // 128 KB
    float*          P   = (float*)        (ws + 0x420000);    // 2 MB
    float*          scal= (float*)        (ws + 0x620000);    // 16 B

    cast_wy_kernel<<<2048, 256, 0, stream>>>(y, w, YQ, WT, scal);
    gemm0_kernel<<<dim3(4, 128), 256, 0, stream>>>(x, WT, XWQ);
    gemm1_kernel<<<dim3(64, 64), 256, 0, stream>>>(XWQ, YQ, P, scal);
    combine_kernel<<<32, 256, 0, stream>>>(P, scal, out);
}